// Round 2
// baseline (1511.027 us; speedup 1.0000x reference)
//
#include <hip/hip_runtime.h>
#include <math.h>

// Llama4 experts + shared LoRA (rank 8), f32 baseline.
// E=8 experts, T=1024 tok/expert, H=1024, I=2048, F2=4096, R=8, scaling=2.
//
// Pipeline:
//   xa     = x @ A_gu^T                      [8192, 8]      (rowdot kernel)
//   hidden = SwiGLU(x @ Wgu[e] + 2*xa@Bgu^T) [8192, 2048]   (gemm1, ws)
//   ha     = hidden @ A_dn^T                 [8192, 8]      (rowdot kernel)
//   out    = hidden @ Wdn[e] + 2*ha@Bdn^T    [8192, 1024]   (gemm2)
//
// GEMM: 128x128 block tile, BK=32, 256 thr, 8x8 micro-tile/thread (vector FMA,
// f32 — no fp32 MFMA on CDNA4). LDS: A-tile transposed [32][132], B-tile [32][132].
// R1 fix: gemm1 W-tile staging only filled wt cols 0..63; inner loop reads 0..127.

#define NE 8
#define TT 1024
#define HH 1024
#define II 2048
#define FF2 4096
#define RR 8
#define NROW (NE * TT) /* 8192 */
#define SCAL 2.0f

// ---------------- rank-8 row dots: xa[t][r] = sum_k x[t][k]*A[r][k] ----------
template <int K>
__global__ __launch_bounds__(256) void rowdot_kernel(const float* __restrict__ x,
                                                     const float* __restrict__ A,
                                                     float* __restrict__ xa) {
  const int w = threadIdx.x >> 6;     // wave in block
  const int lane = threadIdx.x & 63;
  const int t = blockIdx.x * 4 + w;   // one row per wave
  const float* xrow = x + (size_t)t * K;
  float acc[RR];
#pragma unroll
  for (int r = 0; r < RR; ++r) acc[r] = 0.f;
#pragma unroll
  for (int c = 0; c < K / 256; ++c) {
    const float4 xv = *(const float4*)(xrow + c * 256 + lane * 4);
#pragma unroll
    for (int r = 0; r < RR; ++r) {
      const float4 av = *(const float4*)(A + (size_t)r * K + c * 256 + lane * 4);
      acc[r] += xv.x * av.x + xv.y * av.y + xv.z * av.z + xv.w * av.w;
    }
  }
#pragma unroll
  for (int r = 0; r < RR; ++r) {
    float v = acc[r];
#pragma unroll
    for (int off = 32; off > 0; off >>= 1) v += __shfl_down(v, off, 64);
    if (lane == 0) xa[(size_t)t * RR + r] = v;
  }
}

// ---------------- gemm1: hidden = SwiGLU(x@Wgu + 2*xa@Bgu^T) ----------------
// Block covers 128 rows x (64 gate cols + matching 64 up cols).
__global__ __launch_bounds__(256) void gemm1_kernel(const float* __restrict__ x,
                                                    const float* __restrict__ Wgu,
                                                    const float* __restrict__ xa,
                                                    const float* __restrict__ Bgu,
                                                    float* __restrict__ hidden) {
  __shared__ float xs[32][132];  // [k][t] transposed
  __shared__ float wt[32][132];  // [k][c]; c<64: gate col i0+c, c>=64: up col I+i0+(c-64)

  const int bid = blockIdx.x;
  const int nIT = II / 64;  // 32
  const int nTT = TT / 128; // 8
  const int e = bid / (nIT * nTT);
  const int rem = bid % (nIT * nTT);
  const int tt = rem / nIT;
  const int it = rem % nIT;
  const int t0 = e * TT + tt * 128;
  const int i0 = it * 64;
  const float* Wg = Wgu + (size_t)e * HH * FF2;

  const int tid = threadIdx.x;
  const int rg = tid >> 4, cg = tid & 15;
  const int tr = rg * 8, tc = cg * 4;

  float acc[8][8];
#pragma unroll
  for (int i = 0; i < 8; ++i)
#pragma unroll
    for (int j = 0; j < 8; ++j) acc[i][j] = 0.f;

  for (int k0 = 0; k0 < HH; k0 += 32) {
    // stage X tile (transposed into xs): 128 rows x 32 k
#pragma unroll
    for (int l = 0; l < 4; ++l) {
      const int idx = tid + l * 256;
      const int row = idx >> 3, c4 = idx & 7;
      const float4 v = *(const float4*)(x + (size_t)(t0 + row) * HH + k0 + c4 * 4);
      xs[c4 * 4 + 0][row] = v.x;
      xs[c4 * 4 + 1][row] = v.y;
      xs[c4 * 4 + 2][row] = v.z;
      xs[c4 * 4 + 3][row] = v.w;
    }
    // stage W tile: 32 k x 128 cols (64 gate + 64 up)
#pragma unroll
    for (int l = 0; l < 4; ++l) {
      const int idx = tid + l * 256;            // 0..1023
      const int kr = idx >> 5, c = idx & 31;    // kr 0..31, c 0..31 (x4 floats)
      const int col = (c < 16) ? (i0 + c * 4) : (II + i0 + (c - 16) * 4);
      const float4 v = *(const float4*)(Wg + (size_t)(k0 + kr) * FF2 + col);
      *(float4*)&wt[kr][c * 4] = v;
    }
    __syncthreads();
#pragma unroll 4
    for (int k = 0; k < 32; ++k) {
      const float4 a0 = *(const float4*)&xs[k][tr];
      const float4 a1 = *(const float4*)&xs[k][tr + 4];
      const float4 b0 = *(const float4*)&wt[k][tc];
      const float4 b1 = *(const float4*)&wt[k][64 + tc];
      const float av[8] = {a0.x, a0.y, a0.z, a0.w, a1.x, a1.y, a1.z, a1.w};
      const float bv[8] = {b0.x, b0.y, b0.z, b0.w, b1.x, b1.y, b1.z, b1.w};
#pragma unroll
      for (int i = 0; i < 8; ++i)
#pragma unroll
        for (int j = 0; j < 8; ++j) acc[i][j] += av[i] * bv[j];
    }
    __syncthreads();
  }

  // epilogue: add rank-8 LoRA, SwiGLU, store hidden
  const float4* xa4 = (const float4*)xa;
  const float4* B4 = (const float4*)Bgu;
#pragma unroll
  for (int i = 0; i < 8; ++i) {
    const int t = t0 + tr + i;
    const float4 xr0 = xa4[t * 2], xr1 = xa4[t * 2 + 1];
    float o[4];
#pragma unroll
    for (int j = 0; j < 4; ++j) {
      const int fg = i0 + tc + j;
      const int fu = II + fg;
      const float4 bg0 = B4[fg * 2], bg1 = B4[fg * 2 + 1];
      const float4 bu0 = B4[fu * 2], bu1 = B4[fu * 2 + 1];
      const float lg = xr0.x * bg0.x + xr0.y * bg0.y + xr0.z * bg0.z + xr0.w * bg0.w +
                       xr1.x * bg1.x + xr1.y * bg1.y + xr1.z * bg1.z + xr1.w * bg1.w;
      const float lu = xr0.x * bu0.x + xr0.y * bu0.y + xr0.z * bu0.z + xr0.w * bu0.w +
                       xr1.x * bu1.x + xr1.y * bu1.y + xr1.z * bu1.z + xr1.w * bu1.w;
      const float g = acc[i][j] + SCAL * lg;
      const float u = acc[i][4 + j] + SCAL * lu;
      const float sg = g / (1.f + __expf(-g));  // silu
      o[j] = u * sg;
    }
    *(float4*)(hidden + (size_t)t * II + i0 + tc) = make_float4(o[0], o[1], o[2], o[3]);
  }
}

// ---------------- gemm2: out = hidden@Wdn + 2*ha@Bdn^T ----------------------
__global__ __launch_bounds__(256) void gemm2_kernel(const float* __restrict__ hidden,
                                                    const float* __restrict__ Wdn,
                                                    const float* __restrict__ ha,
                                                    const float* __restrict__ Bdn,
                                                    float* __restrict__ out) {
  __shared__ float hs[32][132];  // [k][t]
  __shared__ float wt[32][132];  // [k][c], c in 0..127 -> h0+c

  const int bid = blockIdx.x;
  const int nHT = HH / 128; // 8
  const int nTT = TT / 128; // 8
  const int e = bid / (nHT * nTT);
  const int rem = bid % (nHT * nTT);
  const int tt = rem / nHT;
  const int ht = rem % nHT;
  const int t0 = e * TT + tt * 128;
  const int h0 = ht * 128;
  const float* Wd = Wdn + (size_t)e * II * HH;

  const int tid = threadIdx.x;
  const int rg = tid >> 4, cg = tid & 15;
  const int tr = rg * 8, tc = cg * 4;

  float acc[8][8];
#pragma unroll
  for (int i = 0; i < 8; ++i)
#pragma unroll
    for (int j = 0; j < 8; ++j) acc[i][j] = 0.f;

  for (int k0 = 0; k0 < II; k0 += 32) {
#pragma unroll
    for (int l = 0; l < 4; ++l) {
      const int idx = tid + l * 256;
      const int row = idx >> 3, c4 = idx & 7;
      const float4 v = *(const float4*)(hidden + (size_t)(t0 + row) * II + k0 + c4 * 4);
      hs[c4 * 4 + 0][row] = v.x;
      hs[c4 * 4 + 1][row] = v.y;
      hs[c4 * 4 + 2][row] = v.z;
      hs[c4 * 4 + 3][row] = v.w;
    }
#pragma unroll
    for (int l = 0; l < 4; ++l) {
      const int idx = tid + l * 256;
      const int kr = idx >> 5, c4 = idx & 31;
      const float4 v = *(const float4*)(Wd + (size_t)(k0 + kr) * HH + h0 + c4 * 4);
      *(float4*)&wt[kr][c4 * 4] = v;
    }
    __syncthreads();
#pragma unroll 4
    for (int k = 0; k < 32; ++k) {
      const float4 a0 = *(const float4*)&hs[k][tr];
      const float4 a1 = *(const float4*)&hs[k][tr + 4];
      const float4 b0 = *(const float4*)&wt[k][tc];
      const float4 b1 = *(const float4*)&wt[k][64 + tc];
      const float av[8] = {a0.x, a0.y, a0.z, a0.w, a1.x, a1.y, a1.z, a1.w};
      const float bv[8] = {b0.x, b0.y, b0.z, b0.w, b1.x, b1.y, b1.z, b1.w};
#pragma unroll
      for (int i = 0; i < 8; ++i)
#pragma unroll
        for (int j = 0; j < 8; ++j) acc[i][j] += av[i] * bv[j];
    }
    __syncthreads();
  }

  const float4* ha4 = (const float4*)ha;
  const float4* B4 = (const float4*)Bdn;
#pragma unroll
  for (int i = 0; i < 8; ++i) {
    const int t = t0 + tr + i;
    const float4 hr0 = ha4[t * 2], hr1 = ha4[t * 2 + 1];
    float o[8];
#pragma unroll
    for (int jj = 0; jj < 8; ++jj) {
      const int c = (jj < 4) ? (tc + jj) : (64 + tc + (jj - 4));
      const int h = h0 + c;
      const float4 b0 = B4[h * 2], b1 = B4[h * 2 + 1];
      const float l = hr0.x * b0.x + hr0.y * b0.y + hr0.z * b0.z + hr0.w * b0.w +
                      hr1.x * b1.x + hr1.y * b1.y + hr1.z * b1.z + hr1.w * b1.w;
      o[jj] = acc[i][jj] + SCAL * l;
    }
    *(float4*)(out + (size_t)t * HH + h0 + tc) = make_float4(o[0], o[1], o[2], o[3]);
    *(float4*)(out + (size_t)t * HH + h0 + 64 + tc) = make_float4(o[4], o[5], o[6], o[7]);
  }
}

extern "C" void kernel_launch(void* const* d_in, const int* in_sizes, int n_in,
                              void* d_out, int out_size, void* d_ws, size_t ws_size,
                              hipStream_t stream) {
  const float* x   = (const float*)d_in[0];  // [8192,1024]
  const float* Wgu = (const float*)d_in[1];  // [8,1024,4096]
  const float* Wdn = (const float*)d_in[2];  // [8,2048,1024]
  const float* Agu = (const float*)d_in[3];  // [8,1024]
  const float* Bgu = (const float*)d_in[4];  // [4096,8]
  const float* Adn = (const float*)d_in[5];  // [8,2048]
  const float* Bdn = (const float*)d_in[6];  // [1024,8]
  float* out = (float*)d_out;

  float* hidden = (float*)d_ws;                       // 8192*2048 f32 = 64 MB
  float* xa = hidden + (size_t)NROW * II;             // 8192*8
  float* ha = xa + (size_t)NROW * RR;                 // 8192*8

  rowdot_kernel<HH><<<NROW / 4, 256, 0, stream>>>(x, Agu, xa);
  gemm1_kernel<<<NE * (TT / 128) * (II / 64), 256, 0, stream>>>(x, Wgu, xa, Bgu, hidden);
  rowdot_kernel<II><<<NROW / 4, 256, 0, stream>>>(hidden, Adn, ha);
  gemm2_kernel<<<NE * (TT / 128) * (HH / 128), 256, 0, stream>>>(hidden, Wdn, ha, Bdn, out);
}

// Round 3
// 618.000 us; speedup vs baseline: 2.4450x; 2.4450x over previous
//
#include <hip/hip_runtime.h>
#include <math.h>

// Llama4 experts + shared LoRA (rank 8) — bf16 MFMA version.
// E=8, T=1024, H=1024, I=2048, F2=4096, R=8, scaling=2.
//
//   xa     = x @ A_gu^T                       [8192,8]    f32 rowdot
//   hidden = SwiGLU(x@Wgu + 2*xa@Bgu^T)       [8192,2048] bf16 (ws), MFMA gemm1
//   ha     = hidden @ A_dn^T                  [8192,8]    bf16 rowdot
//   out    = hidden@Wdn + 2*ha@Bdn^T          [8192,1024] f32, MFMA gemm2
//
// GEMM: 128x128 tile, BK=32, 256 thr (4 waves, each 64x64 via 4x4 16x16x32
// MFMA frags, f32 accum). f32->bf16 conversion reg-staged into padded LDS
// (stride 40 elems = 80B: b128 frag reads conflict-free). LoRA + SwiGLU in f32.

#define NE 8
#define TT 1024
#define HH 1024
#define II 2048
#define FF2 4096
#define RR 8
#define NROW (NE * TT)
#define SCAL 2.0f

typedef __bf16 bf16x8 __attribute__((ext_vector_type(8)));
typedef float f32x4 __attribute__((ext_vector_type(4)));

__device__ __forceinline__ unsigned short f2bf(float f) {
  unsigned int u = __float_as_uint(f);
  u += 0x7fffu + ((u >> 16) & 1u);  // RNE
  return (unsigned short)(u >> 16);
}
__device__ __forceinline__ float dot4(float4 a, float4 b) {
  return a.x * b.x + a.y * b.y + a.z * b.z + a.w * b.w;
}

// ---------------- xa = x @ A^T (f32 input) ----------------------------------
template <int K>
__global__ __launch_bounds__(256) void rowdot_kernel(const float* __restrict__ x,
                                                     const float* __restrict__ A,
                                                     float* __restrict__ xa) {
  const int w = threadIdx.x >> 6;
  const int lane = threadIdx.x & 63;
  const int t = blockIdx.x * 4 + w;
  const float* xrow = x + (size_t)t * K;
  float acc[RR];
#pragma unroll
  for (int r = 0; r < RR; ++r) acc[r] = 0.f;
#pragma unroll
  for (int c = 0; c < K / 256; ++c) {
    const float4 xv = *(const float4*)(xrow + c * 256 + lane * 4);
#pragma unroll
    for (int r = 0; r < RR; ++r) {
      const float4 av = *(const float4*)(A + (size_t)r * K + c * 256 + lane * 4);
      acc[r] += dot4(xv, av);
    }
  }
#pragma unroll
  for (int r = 0; r < RR; ++r) {
    float v = acc[r];
#pragma unroll
    for (int off = 32; off > 0; off >>= 1) v += __shfl_down(v, off, 64);
    if (lane == 0) xa[(size_t)t * RR + r] = v;
  }
}

// ---------------- ha = hidden(bf16) @ A^T -----------------------------------
__global__ __launch_bounds__(256) void rowdot_bf16_kernel(const unsigned short* __restrict__ h,
                                                          const float* __restrict__ A,
                                                          float* __restrict__ ha) {
  const int w = threadIdx.x >> 6;
  const int lane = threadIdx.x & 63;
  const int t = blockIdx.x * 4 + w;
  const unsigned short* hrow = h + (size_t)t * II;
  float acc[RR];
#pragma unroll
  for (int r = 0; r < RR; ++r) acc[r] = 0.f;
#pragma unroll
  for (int c = 0; c < II / 512; ++c) {  // 4 iters, 8 bf16/lane each
    const uint4 v = *(const uint4*)(hrow + c * 512 + lane * 8);
    float xv[8];
    xv[0] = __uint_as_float(v.x << 16); xv[1] = __uint_as_float(v.x & 0xffff0000u);
    xv[2] = __uint_as_float(v.y << 16); xv[3] = __uint_as_float(v.y & 0xffff0000u);
    xv[4] = __uint_as_float(v.z << 16); xv[5] = __uint_as_float(v.z & 0xffff0000u);
    xv[6] = __uint_as_float(v.w << 16); xv[7] = __uint_as_float(v.w & 0xffff0000u);
#pragma unroll
    for (int r = 0; r < RR; ++r) {
      const float4 a0 = *(const float4*)(A + (size_t)r * II + c * 512 + lane * 8);
      const float4 a1 = *(const float4*)(A + (size_t)r * II + c * 512 + lane * 8 + 4);
      acc[r] += xv[0] * a0.x + xv[1] * a0.y + xv[2] * a0.z + xv[3] * a0.w +
                xv[4] * a1.x + xv[5] * a1.y + xv[6] * a1.z + xv[7] * a1.w;
    }
  }
#pragma unroll
  for (int r = 0; r < RR; ++r) {
    float v = acc[r];
#pragma unroll
    for (int off = 32; off > 0; off >>= 1) v += __shfl_down(v, off, 64);
    if (lane == 0) ha[(size_t)t * RR + r] = v;
  }
}

// ---------------- gemm1: hidden = SwiGLU(x@Wgu + 2*xa@Bgu^T), bf16 out ------
__global__ __launch_bounds__(256) void gemm1_kernel(const float* __restrict__ x,
                                                    const float* __restrict__ Wgu,
                                                    const float* __restrict__ xa,
                                                    const float* __restrict__ Bgu,
                                                    unsigned short* __restrict__ hidden) {
  __shared__ unsigned short As[128][40];  // [token row][k], pad->80B stride
  __shared__ unsigned short Bs[128][40];  // [out col][k]; col<64 gate, >=64 up

  const int bid = blockIdx.x;
  const int e = bid >> 8;        // 256 blocks/expert
  const int rem = bid & 255;
  const int tt = rem >> 5;       // 8 row tiles
  const int it = rem & 31;       // 32 col tiles (64 gate+64 up cols each)
  const int t0 = e * TT + tt * 128;
  const int i0 = it * 64;
  const float* Wg = Wgu + (size_t)e * HH * FF2;

  const int tid = threadIdx.x;
  const int w = tid >> 6, lane = tid & 63;
  const int wr = w >> 1, wc = w & 1;
  const int lrow = lane & 15, lk = (lane >> 4) * 8;

  f32x4 acc[4][4];
#pragma unroll
  for (int i = 0; i < 4; ++i)
#pragma unroll
    for (int j = 0; j < 4; ++j) acc[i][j] = (f32x4)(0.f);

  for (int k0 = 0; k0 < HH; k0 += 32) {
    // stage A: x f32 -> bf16, [128 rows][32 k]
#pragma unroll
    for (int l = 0; l < 4; ++l) {
      const int idx = tid + l * 256;  // 0..1023
      const int row = idx >> 3, kq = idx & 7;
      const float4 v = *(const float4*)(x + (size_t)(t0 + row) * HH + k0 + kq * 4);
      ushort4 p;
      p.x = f2bf(v.x); p.y = f2bf(v.y); p.z = f2bf(v.z); p.w = f2bf(v.w);
      *(ushort4*)&As[row][kq * 4] = p;
    }
    // stage B: Wg strided-k loads (lanes = consecutive cols, coalesced)
#pragma unroll
    for (int l = 0; l < 2; ++l) {
      const int idx = tid + l * 256;       // 0..511
      const int col = idx & 127, kq8 = idx >> 7;  // kq8 0..3
      const int gcol = i0 + (col & 63) + ((col >> 6) * II);
      union { unsigned short u[8]; uint4 v; } pk;
#pragma unroll
      for (int kk = 0; kk < 8; ++kk) {
        const float f = Wg[(size_t)(k0 + kq8 * 8 + kk) * FF2 + gcol];
        pk.u[kk] = f2bf(f);
      }
      *(uint4*)&Bs[col][kq8 * 8] = pk.v;
    }
    __syncthreads();
    bf16x8 af[4], bf[4];
#pragma unroll
    for (int mi = 0; mi < 4; ++mi)
      af[mi] = *(const bf16x8*)&As[wr * 64 + mi * 16 + lrow][lk];
#pragma unroll
    for (int nj = 0; nj < 4; ++nj) {
      const int c = (nj < 2) ? (wc * 32 + nj * 16) : (64 + wc * 32 + (nj - 2) * 16);
      bf[nj] = *(const bf16x8*)&Bs[c + lrow][lk];
    }
#pragma unroll
    for (int mi = 0; mi < 4; ++mi)
#pragma unroll
      for (int nj = 0; nj < 4; ++nj)
        acc[mi][nj] = __builtin_amdgcn_mfma_f32_16x16x32_bf16(af[mi], bf[nj], acc[mi][nj], 0, 0, 0);
    __syncthreads();
  }

  // epilogue: LoRA (f32) + SwiGLU, store bf16 hidden
  const float4* xa4 = (const float4*)xa;
  const float4* B4 = (const float4*)Bgu;
#pragma unroll
  for (int nj = 0; nj < 2; ++nj) {
    const int coln = i0 + wc * 32 + nj * 16 + lrow;  // hidden col in [0,II)
    const float4 bg0 = B4[coln * 2], bg1 = B4[coln * 2 + 1];
    const float4 bu0 = B4[(II + coln) * 2], bu1 = B4[(II + coln) * 2 + 1];
#pragma unroll
    for (int mi = 0; mi < 4; ++mi) {
      const int tb = t0 + wr * 64 + mi * 16 + (lane >> 4) * 4;
#pragma unroll
      for (int j = 0; j < 4; ++j) {
        const int t = tb + j;
        const float4 xr0 = xa4[t * 2], xr1 = xa4[t * 2 + 1];
        const float lg = dot4(xr0, bg0) + dot4(xr1, bg1);
        const float lu = dot4(xr0, bu0) + dot4(xr1, bu1);
        const float g = acc[mi][nj][j] + SCAL * lg;
        const float u = acc[mi][nj + 2][j] + SCAL * lu;
        const float s = g / (1.f + __expf(-g));
        hidden[(size_t)t * II + coln] = f2bf(u * s);
      }
    }
  }
}

// ---------------- gemm2: out = hidden@Wdn + 2*ha@Bdn^T (f32 out) ------------
__global__ __launch_bounds__(256) void gemm2_kernel(const unsigned short* __restrict__ hid,
                                                    const float* __restrict__ Wdn,
                                                    const float* __restrict__ ha,
                                                    const float* __restrict__ Bdn,
                                                    float* __restrict__ out) {
  __shared__ unsigned short As[128][40];
  __shared__ unsigned short Bs[128][40];

  const int bid = blockIdx.x;
  const int e = bid >> 6;        // 64 blocks/expert
  const int rem = bid & 63;
  const int tt = rem >> 3;       // 8 row tiles
  const int ht = rem & 7;        // 8 col tiles (128 cols)
  const int t0 = e * TT + tt * 128;
  const int h0 = ht * 128;
  const float* Wd = Wdn + (size_t)e * II * HH;

  const int tid = threadIdx.x;
  const int w = tid >> 6, lane = tid & 63;
  const int wr = w >> 1, wc = w & 1;
  const int lrow = lane & 15, lk = (lane >> 4) * 8;

  f32x4 acc[4][4];
#pragma unroll
  for (int i = 0; i < 4; ++i)
#pragma unroll
    for (int j = 0; j < 4; ++j) acc[i][j] = (f32x4)(0.f);

  for (int k0 = 0; k0 < II; k0 += 32) {
    // stage A: hidden already bf16, direct 16B copies
#pragma unroll
    for (int l = 0; l < 2; ++l) {
      const int idx = tid + l * 256;  // 0..511
      const int row = idx >> 2, kq8 = idx & 3;
      *(uint4*)&As[row][kq8 * 8] =
          *(const uint4*)(hid + (size_t)(t0 + row) * II + k0 + kq8 * 8);
    }
    // stage B: Wd strided-k loads
#pragma unroll
    for (int l = 0; l < 2; ++l) {
      const int idx = tid + l * 256;
      const int col = idx & 127, kq8 = idx >> 7;
      const int gcol = h0 + col;
      union { unsigned short u[8]; uint4 v; } pk;
#pragma unroll
      for (int kk = 0; kk < 8; ++kk) {
        const float f = Wd[(size_t)(k0 + kq8 * 8 + kk) * HH + gcol];
        pk.u[kk] = f2bf(f);
      }
      *(uint4*)&Bs[col][kq8 * 8] = pk.v;
    }
    __syncthreads();
    bf16x8 af[4], bf[4];
#pragma unroll
    for (int mi = 0; mi < 4; ++mi)
      af[mi] = *(const bf16x8*)&As[wr * 64 + mi * 16 + lrow][lk];
#pragma unroll
    for (int nj = 0; nj < 4; ++nj)
      bf[nj] = *(const bf16x8*)&Bs[wc * 64 + nj * 16 + lrow][lk];
#pragma unroll
    for (int mi = 0; mi < 4; ++mi)
#pragma unroll
      for (int nj = 0; nj < 4; ++nj)
        acc[mi][nj] = __builtin_amdgcn_mfma_f32_16x16x32_bf16(af[mi], bf[nj], acc[mi][nj], 0, 0, 0);
    __syncthreads();
  }

  const float4* ha4 = (const float4*)ha;
  const float4* B4 = (const float4*)Bdn;
#pragma unroll
  for (int nj = 0; nj < 4; ++nj) {
    const int coln = h0 + wc * 64 + nj * 16 + lrow;  // out col in [0,HH)
    const float4 b0 = B4[coln * 2], b1 = B4[coln * 2 + 1];
#pragma unroll
    for (int mi = 0; mi < 4; ++mi) {
      const int tb = t0 + wr * 64 + mi * 16 + (lane >> 4) * 4;
#pragma unroll
      for (int j = 0; j < 4; ++j) {
        const int t = tb + j;
        const float4 hr0 = ha4[t * 2], hr1 = ha4[t * 2 + 1];
        out[(size_t)t * HH + coln] = acc[mi][nj][j] + SCAL * (dot4(hr0, b0) + dot4(hr1, b1));
      }
    }
  }
}

extern "C" void kernel_launch(void* const* d_in, const int* in_sizes, int n_in,
                              void* d_out, int out_size, void* d_ws, size_t ws_size,
                              hipStream_t stream) {
  const float* x   = (const float*)d_in[0];
  const float* Wgu = (const float*)d_in[1];
  const float* Wdn = (const float*)d_in[2];
  const float* Agu = (const float*)d_in[3];
  const float* Bgu = (const float*)d_in[4];
  const float* Adn = (const float*)d_in[5];
  const float* Bdn = (const float*)d_in[6];
  float* out = (float*)d_out;

  unsigned short* hidden = (unsigned short*)d_ws;              // 8192*2048 bf16 = 32 MB
  float* xa = (float*)((char*)d_ws + (size_t)NROW * II * 2);   // 8192*8 f32
  float* ha = xa + (size_t)NROW * RR;

  rowdot_kernel<HH><<<NROW / 4, 256, 0, stream>>>(x, Agu, xa);
  gemm1_kernel<<<NE * 8 * 32, 256, 0, stream>>>(x, Wgu, xa, Bgu, hidden);
  rowdot_bf16_kernel<<<NROW / 4, 256, 0, stream>>>(hidden, Adn, ha);
  gemm2_kernel<<<NE * 8 * 8, 256, 0, stream>>>(hidden, Wdn, ha, Bdn, out);
}

// Round 4
// 489.087 us; speedup vs baseline: 3.0895x; 1.2636x over previous
//
#include <hip/hip_runtime.h>
#include <math.h>

// Llama4 experts + shared LoRA (rank 8) — bf16 MFMA, pre-converted weights.
// E=8, T=1024, H=1024, I=2048, F2=4096, R=8, scaling=2.
//
// Main path (needs ~144.5 MB ws):
//   convx      : xb = bf16(x)                          [8192,1024]
//   transconv  : WguT = bf16(Wgu^T) gate/up-interleaved [8,4096,1024]
//                WdnT = bf16(Wdn^T)                     [8,1024,2048]
//   xa = x @ A_gu^T (f32)
//   gemm1_bt   : hidden = SwiGLU(xb@WguT^T + LoRA)      bf16, m97-style
//   ha = hidden @ A_dn^T
//   gemm2_bt   : out = hidden@WdnT^T + LoRA             f32
// GEMM: 128x128 tile, BK=64, 256 thr, global_load_lds(16B) staging, linear LDS,
// 2-barrier K-loop, 4 waves x (4x4) mfma_f32_16x16x32_bf16, f32 accum.
// Fallback (ws < needed): R3 kernels (in-loop conversion).

#define NE 8
#define TT 1024
#define HH 1024
#define II 2048
#define FF2 4096
#define RR 8
#define NROW (NE * TT)
#define SCAL 2.0f

typedef __bf16 bf16x8 __attribute__((ext_vector_type(8)));
typedef float f32x4 __attribute__((ext_vector_type(4)));

#define GLOAD16(g, l)                                                        \
  __builtin_amdgcn_global_load_lds((const __attribute__((address_space(1))) void*)(g), \
                                   (__attribute__((address_space(3))) void*)(l), 16, 0, 0)

__device__ __forceinline__ unsigned short f2bf(float f) {
  unsigned int u = __float_as_uint(f);
  u += 0x7fffu + ((u >> 16) & 1u);  // RNE
  return (unsigned short)(u >> 16);
}
__device__ __forceinline__ float dot4(float4 a, float4 b) {
  return a.x * b.x + a.y * b.y + a.z * b.z + a.w * b.w;
}

// ---------------- conversion pre-passes -------------------------------------
__global__ __launch_bounds__(256) void convx_kernel(const float* __restrict__ x,
                                                    unsigned short* __restrict__ xb) {
  const int i = blockIdx.x * 256 + threadIdx.x;  // 8-elem chunk index
  const float4 a = *(const float4*)(x + (size_t)i * 8);
  const float4 b = *(const float4*)(x + (size_t)i * 8 + 4);
  union { unsigned short u[8]; uint4 v; } pk;
  pk.u[0] = f2bf(a.x); pk.u[1] = f2bf(a.y); pk.u[2] = f2bf(a.z); pk.u[3] = f2bf(a.w);
  pk.u[4] = f2bf(b.x); pk.u[5] = f2bf(b.y); pk.u[6] = f2bf(b.z); pk.u[7] = f2bf(b.w);
  *(uint4*)(xb + (size_t)i * 8) = pk.v;
}

// Wgu [e][1024][4096] f32 -> WguT [e][4096][1024] bf16, gate/up interleaved:
// out row n' = t*128+j for gate n=t*64+j; n' = t*128+64+j for up n=2048+t*64+j.
__global__ __launch_bounds__(256) void transconv_gu_kernel(const float* __restrict__ W,
                                                           unsigned short* __restrict__ WT) {
  __shared__ float ts[64][65];
  const int bid = blockIdx.x;           // 8*16*64
  const int nt = bid & 63, kt = (bid >> 6) & 15, e = bid >> 10;
  const float* Win = W + (size_t)e * HH * FF2 + (size_t)(kt * 64) * FF2 + nt * 64;
  const int tid = threadIdx.x;
#pragma unroll
  for (int l = 0; l < 4; ++l) {
    const int idx = tid + l * 256, r = idx >> 4, c4 = idx & 15;
    const float4 v = *(const float4*)(Win + (size_t)r * FF2 + c4 * 4);
    ts[r][c4 * 4 + 0] = v.x; ts[r][c4 * 4 + 1] = v.y;
    ts[r][c4 * 4 + 2] = v.z; ts[r][c4 * 4 + 3] = v.w;
  }
  __syncthreads();
  const int npb = (nt < 32) ? nt * 128 : (nt - 32) * 128 + 64;
  unsigned short* Wout = WT + (size_t)e * FF2 * HH + (size_t)npb * HH + kt * 64;
#pragma unroll
  for (int l = 0; l < 2; ++l) {
    const int idx = tid + l * 256, j = idx >> 3, q = idx & 7;
    union { unsigned short u[8]; uint4 v; } pk;
#pragma unroll
    for (int kk = 0; kk < 8; ++kk) pk.u[kk] = f2bf(ts[q * 8 + kk][j]);
    *(uint4*)(Wout + (size_t)j * HH + q * 8) = pk.v;
  }
}

// Wdn [e][2048][1024] f32 -> WdnT [e][1024][2048] bf16 (plain transpose).
__global__ __launch_bounds__(256) void transconv_dn_kernel(const float* __restrict__ W,
                                                           unsigned short* __restrict__ WT) {
  __shared__ float ts[64][65];
  const int bid = blockIdx.x;           // 8*32*16
  const int nt = bid & 15, kt = (bid >> 4) & 31, e = bid >> 9;
  const float* Win = W + (size_t)e * II * HH + (size_t)(kt * 64) * HH + nt * 64;
  const int tid = threadIdx.x;
#pragma unroll
  for (int l = 0; l < 4; ++l) {
    const int idx = tid + l * 256, r = idx >> 4, c4 = idx & 15;
    const float4 v = *(const float4*)(Win + (size_t)r * HH + c4 * 4);
    ts[r][c4 * 4 + 0] = v.x; ts[r][c4 * 4 + 1] = v.y;
    ts[r][c4 * 4 + 2] = v.z; ts[r][c4 * 4 + 3] = v.w;
  }
  __syncthreads();
  unsigned short* Wout = WT + (size_t)e * HH * II + (size_t)(nt * 64) * II + kt * 64;
#pragma unroll
  for (int l = 0; l < 2; ++l) {
    const int idx = tid + l * 256, j = idx >> 3, q = idx & 7;
    union { unsigned short u[8]; uint4 v; } pk;
#pragma unroll
    for (int kk = 0; kk < 8; ++kk) pk.u[kk] = f2bf(ts[q * 8 + kk][j]);
    *(uint4*)(Wout + (size_t)j * II + q * 8) = pk.v;
  }
}

// ---------------- rank-8 row dots -------------------------------------------
template <int K>
__global__ __launch_bounds__(256) void rowdot_kernel(const float* __restrict__ x,
                                                     const float* __restrict__ A,
                                                     float* __restrict__ xa) {
  const int w = threadIdx.x >> 6, lane = threadIdx.x & 63;
  const int t = blockIdx.x * 4 + w;
  const float* xrow = x + (size_t)t * K;
  float acc[RR];
#pragma unroll
  for (int r = 0; r < RR; ++r) acc[r] = 0.f;
#pragma unroll
  for (int c = 0; c < K / 256; ++c) {
    const float4 xv = *(const float4*)(xrow + c * 256 + lane * 4);
#pragma unroll
    for (int r = 0; r < RR; ++r) {
      const float4 av = *(const float4*)(A + (size_t)r * K + c * 256 + lane * 4);
      acc[r] += dot4(xv, av);
    }
  }
#pragma unroll
  for (int r = 0; r < RR; ++r) {
    float v = acc[r];
#pragma unroll
    for (int off = 32; off > 0; off >>= 1) v += __shfl_down(v, off, 64);
    if (lane == 0) xa[(size_t)t * RR + r] = v;
  }
}

__global__ __launch_bounds__(256) void rowdot_bf16_kernel(const unsigned short* __restrict__ h,
                                                          const float* __restrict__ A,
                                                          float* __restrict__ ha) {
  const int w = threadIdx.x >> 6, lane = threadIdx.x & 63;
  const int t = blockIdx.x * 4 + w;
  const unsigned short* hrow = h + (size_t)t * II;
  float acc[RR];
#pragma unroll
  for (int r = 0; r < RR; ++r) acc[r] = 0.f;
#pragma unroll
  for (int c = 0; c < II / 512; ++c) {
    const uint4 v = *(const uint4*)(hrow + c * 512 + lane * 8);
    float xv[8];
    xv[0] = __uint_as_float(v.x << 16); xv[1] = __uint_as_float(v.x & 0xffff0000u);
    xv[2] = __uint_as_float(v.y << 16); xv[3] = __uint_as_float(v.y & 0xffff0000u);
    xv[4] = __uint_as_float(v.z << 16); xv[5] = __uint_as_float(v.z & 0xffff0000u);
    xv[6] = __uint_as_float(v.w << 16); xv[7] = __uint_as_float(v.w & 0xffff0000u);
#pragma unroll
    for (int r = 0; r < RR; ++r) {
      const float4 a0 = *(const float4*)(A + (size_t)r * II + c * 512 + lane * 8);
      const float4 a1 = *(const float4*)(A + (size_t)r * II + c * 512 + lane * 8 + 4);
      acc[r] += xv[0] * a0.x + xv[1] * a0.y + xv[2] * a0.z + xv[3] * a0.w +
                xv[4] * a1.x + xv[5] * a1.y + xv[6] * a1.z + xv[7] * a1.w;
    }
  }
#pragma unroll
  for (int r = 0; r < RR; ++r) {
    float v = acc[r];
#pragma unroll
    for (int off = 32; off > 0; off >>= 1) v += __shfl_down(v, off, 64);
    if (lane == 0) ha[(size_t)t * RR + r] = v;
  }
}

// ---------------- gemm1_bt: hidden = SwiGLU(xb@WguT^T + LoRA) ---------------
__global__ __launch_bounds__(256) void gemm1_bt_kernel(const unsigned short* __restrict__ xb,
                                                       const unsigned short* __restrict__ WguT,
                                                       const float* __restrict__ xa,
                                                       const float* __restrict__ Bgu,
                                                       unsigned short* __restrict__ hidden) {
  __shared__ unsigned short As[128 * 64];  // [row][64k] linear, 16 KB
  __shared__ unsigned short Bs[128 * 64];

  const int bid = blockIdx.x;        // 8 * 8 * 32
  const int e = bid >> 8, tt = (bid >> 5) & 7, it = bid & 31;
  const int t0 = e * TT + tt * 128;
  const int i0 = it * 64;            // hidden-col base (gate index)
  const unsigned short* Aexp = xb + (size_t)t0 * HH;
  const unsigned short* Bexp = WguT + (size_t)e * FF2 * HH + (size_t)(it * 128) * HH;

  const int tid = threadIdx.x;
  const int w = tid >> 6, lane = tid & 63;
  const int wr = w >> 1, wc = w & 1;
  const int lrow = lane & 15, lk = (lane >> 4) * 8;
  char* AsB = (char*)As;
  char* BsB = (char*)Bs;
  const int pbase = w * 4096 + lane * 16;

  f32x4 acc[4][4];
#pragma unroll
  for (int i = 0; i < 4; ++i)
#pragma unroll
    for (int j = 0; j < 4; ++j) acc[i][j] = (f32x4)(0.f);

  for (int k0 = 0; k0 < HH; k0 += 64) {
#pragma unroll
    for (int q = 0; q < 4; ++q) {
      const int p = pbase + q * 1024;
      const int row = p >> 7, kb = p & 127;
      GLOAD16((const char*)Aexp + (size_t)row * (HH * 2) + k0 * 2 + kb, AsB + w * 4096 + q * 1024);
      GLOAD16((const char*)Bexp + (size_t)row * (HH * 2) + k0 * 2 + kb, BsB + w * 4096 + q * 1024);
    }
    __syncthreads();
#pragma unroll
    for (int s = 0; s < 2; ++s) {
      bf16x8 af[4], bfr[4];
#pragma unroll
      for (int mi = 0; mi < 4; ++mi)
        af[mi] = *(const bf16x8*)(As + (wr * 64 + mi * 16 + lrow) * 64 + s * 32 + lk);
#pragma unroll
      for (int nj = 0; nj < 4; ++nj) {
        const int jcol = ((nj < 2) ? (wc * 32 + nj * 16) : (64 + wc * 32 + (nj - 2) * 16)) + lrow;
        bfr[nj] = *(const bf16x8*)(Bs + jcol * 64 + s * 32 + lk);
      }
#pragma unroll
      for (int mi = 0; mi < 4; ++mi)
#pragma unroll
        for (int nj = 0; nj < 4; ++nj)
          acc[mi][nj] = __builtin_amdgcn_mfma_f32_16x16x32_bf16(af[mi], bfr[nj], acc[mi][nj], 0, 0, 0);
    }
    __syncthreads();
  }

  const float4* xa4 = (const float4*)xa;
  const float4* B4 = (const float4*)Bgu;
#pragma unroll
  for (int nj = 0; nj < 2; ++nj) {
    const int coln = i0 + wc * 32 + nj * 16 + lrow;  // hidden col
    const float4 bg0 = B4[coln * 2], bg1 = B4[coln * 2 + 1];
    const float4 bu0 = B4[(II + coln) * 2], bu1 = B4[(II + coln) * 2 + 1];
#pragma unroll
    for (int mi = 0; mi < 4; ++mi) {
      const int tb = t0 + wr * 64 + mi * 16 + (lane >> 4) * 4;
#pragma unroll
      for (int j = 0; j < 4; ++j) {
        const int t = tb + j;
        const float4 xr0 = xa4[t * 2], xr1 = xa4[t * 2 + 1];
        const float g = acc[mi][nj][j] + SCAL * (dot4(xr0, bg0) + dot4(xr1, bg1));
        const float u = acc[mi][nj + 2][j] + SCAL * (dot4(xr0, bu0) + dot4(xr1, bu1));
        const float s = g / (1.f + __expf(-g));
        hidden[(size_t)t * II + coln] = f2bf(u * s);
      }
    }
  }
}

// ---------------- gemm2_bt: out = hidden@WdnT^T + LoRA ----------------------
__global__ __launch_bounds__(256) void gemm2_bt_kernel(const unsigned short* __restrict__ hid,
                                                       const unsigned short* __restrict__ WdnT,
                                                       const float* __restrict__ ha,
                                                       const float* __restrict__ Bdn,
                                                       float* __restrict__ out) {
  __shared__ unsigned short As[128 * 64];
  __shared__ unsigned short Bs[128 * 64];

  const int bid = blockIdx.x;        // 8 * 8 * 8
  const int e = bid >> 6, tt = (bid >> 3) & 7, ht = bid & 7;
  const int t0 = e * TT + tt * 128;
  const int h0 = ht * 128;
  const unsigned short* Aexp = hid + (size_t)t0 * II;
  const unsigned short* Bexp = WdnT + (size_t)e * HH * II + (size_t)h0 * II;

  const int tid = threadIdx.x;
  const int w = tid >> 6, lane = tid & 63;
  const int wr = w >> 1, wc = w & 1;
  const int lrow = lane & 15, lk = (lane >> 4) * 8;
  char* AsB = (char*)As;
  char* BsB = (char*)Bs;
  const int pbase = w * 4096 + lane * 16;

  f32x4 acc[4][4];
#pragma unroll
  for (int i = 0; i < 4; ++i)
#pragma unroll
    for (int j = 0; j < 4; ++j) acc[i][j] = (f32x4)(0.f);

  for (int k0 = 0; k0 < II; k0 += 64) {
#pragma unroll
    for (int q = 0; q < 4; ++q) {
      const int p = pbase + q * 1024;
      const int row = p >> 7, kb = p & 127;
      GLOAD16((const char*)Aexp + (size_t)row * (II * 2) + k0 * 2 + kb, AsB + w * 4096 + q * 1024);
      GLOAD16((const char*)Bexp + (size_t)row * (II * 2) + k0 * 2 + kb, BsB + w * 4096 + q * 1024);
    }
    __syncthreads();
#pragma unroll
    for (int s = 0; s < 2; ++s) {
      bf16x8 af[4], bfr[4];
#pragma unroll
      for (int mi = 0; mi < 4; ++mi)
        af[mi] = *(const bf16x8*)(As + (wr * 64 + mi * 16 + lrow) * 64 + s * 32 + lk);
#pragma unroll
      for (int nj = 0; nj < 4; ++nj)
        bfr[nj] = *(const bf16x8*)(Bs + (wc * 64 + nj * 16 + lrow) * 64 + s * 32 + lk);
#pragma unroll
      for (int mi = 0; mi < 4; ++mi)
#pragma unroll
        for (int nj = 0; nj < 4; ++nj)
          acc[mi][nj] = __builtin_amdgcn_mfma_f32_16x16x32_bf16(af[mi], bfr[nj], acc[mi][nj], 0, 0, 0);
    }
    __syncthreads();
  }

  const float4* ha4 = (const float4*)ha;
  const float4* B4 = (const float4*)Bdn;
#pragma unroll
  for (int nj = 0; nj < 4; ++nj) {
    const int coln = h0 + wc * 64 + nj * 16 + lrow;
    const float4 b0 = B4[coln * 2], b1 = B4[coln * 2 + 1];
#pragma unroll
    for (int mi = 0; mi < 4; ++mi) {
      const int tb = t0 + wr * 64 + mi * 16 + (lane >> 4) * 4;
#pragma unroll
      for (int j = 0; j < 4; ++j) {
        const int t = tb + j;
        const float4 hr0 = ha4[t * 2], hr1 = ha4[t * 2 + 1];
        out[(size_t)t * HH + coln] = acc[mi][nj][j] + SCAL * (dot4(hr0, b0) + dot4(hr1, b1));
      }
    }
  }
}

// ---------------- fallback (R3): in-loop conversion GEMMs -------------------
__global__ __launch_bounds__(256) void gemm1_conv_kernel(const float* __restrict__ x,
                                                         const float* __restrict__ Wgu,
                                                         const float* __restrict__ xa,
                                                         const float* __restrict__ Bgu,
                                                         unsigned short* __restrict__ hidden) {
  __shared__ unsigned short As[128][40];
  __shared__ unsigned short Bs[128][40];
  const int bid = blockIdx.x;
  const int e = bid >> 8, rem = bid & 255, tt = rem >> 5, it = rem & 31;
  const int t0 = e * TT + tt * 128, i0 = it * 64;
  const float* Wg = Wgu + (size_t)e * HH * FF2;
  const int tid = threadIdx.x, w = tid >> 6, lane = tid & 63;
  const int wr = w >> 1, wc = w & 1, lrow = lane & 15, lk = (lane >> 4) * 8;
  f32x4 acc[4][4];
#pragma unroll
  for (int i = 0; i < 4; ++i)
#pragma unroll
    for (int j = 0; j < 4; ++j) acc[i][j] = (f32x4)(0.f);
  for (int k0 = 0; k0 < HH; k0 += 32) {
#pragma unroll
    for (int l = 0; l < 4; ++l) {
      const int idx = tid + l * 256, row = idx >> 3, kq = idx & 7;
      const float4 v = *(const float4*)(x + (size_t)(t0 + row) * HH + k0 + kq * 4);
      ushort4 p; p.x = f2bf(v.x); p.y = f2bf(v.y); p.z = f2bf(v.z); p.w = f2bf(v.w);
      *(ushort4*)&As[row][kq * 4] = p;
    }
#pragma unroll
    for (int l = 0; l < 2; ++l) {
      const int idx = tid + l * 256, col = idx & 127, kq8 = idx >> 7;
      const int gcol = i0 + (col & 63) + ((col >> 6) * II);
      union { unsigned short u[8]; uint4 v; } pk;
#pragma unroll
      for (int kk = 0; kk < 8; ++kk) pk.u[kk] = f2bf(Wg[(size_t)(k0 + kq8 * 8 + kk) * FF2 + gcol]);
      *(uint4*)&Bs[col][kq8 * 8] = pk.v;
    }
    __syncthreads();
    bf16x8 af[4], bfr[4];
#pragma unroll
    for (int mi = 0; mi < 4; ++mi) af[mi] = *(const bf16x8*)&As[wr * 64 + mi * 16 + lrow][lk];
#pragma unroll
    for (int nj = 0; nj < 4; ++nj) {
      const int c = (nj < 2) ? (wc * 32 + nj * 16) : (64 + wc * 32 + (nj - 2) * 16);
      bfr[nj] = *(const bf16x8*)&Bs[c + lrow][lk];
    }
#pragma unroll
    for (int mi = 0; mi < 4; ++mi)
#pragma unroll
      for (int nj = 0; nj < 4; ++nj)
        acc[mi][nj] = __builtin_amdgcn_mfma_f32_16x16x32_bf16(af[mi], bfr[nj], acc[mi][nj], 0, 0, 0);
    __syncthreads();
  }
  const float4* xa4 = (const float4*)xa;
  const float4* B4 = (const float4*)Bgu;
#pragma unroll
  for (int nj = 0; nj < 2; ++nj) {
    const int coln = i0 + wc * 32 + nj * 16 + lrow;
    const float4 bg0 = B4[coln * 2], bg1 = B4[coln * 2 + 1];
    const float4 bu0 = B4[(II + coln) * 2], bu1 = B4[(II + coln) * 2 + 1];
#pragma unroll
    for (int mi = 0; mi < 4; ++mi) {
      const int tb = t0 + wr * 64 + mi * 16 + (lane >> 4) * 4;
#pragma unroll
      for (int j = 0; j < 4; ++j) {
        const int t = tb + j;
        const float4 xr0 = xa4[t * 2], xr1 = xa4[t * 2 + 1];
        const float g = acc[mi][nj][j] + SCAL * (dot4(xr0, bg0) + dot4(xr1, bg1));
        const float u = acc[mi][nj + 2][j] + SCAL * (dot4(xr0, bu0) + dot4(xr1, bu1));
        const float s = g / (1.f + __expf(-g));
        hidden[(size_t)t * II + coln] = f2bf(u * s);
      }
    }
  }
}

__global__ __launch_bounds__(256) void gemm2_conv_kernel(const unsigned short* __restrict__ hid,
                                                         const float* __restrict__ Wdn,
                                                         const float* __restrict__ ha,
                                                         const float* __restrict__ Bdn,
                                                         float* __restrict__ out) {
  __shared__ unsigned short As[128][40];
  __shared__ unsigned short Bs[128][40];
  const int bid = blockIdx.x;
  const int e = bid >> 6, rem = bid & 63, tt = rem >> 3, ht = rem & 7;
  const int t0 = e * TT + tt * 128, h0 = ht * 128;
  const float* Wd = Wdn + (size_t)e * II * HH;
  const int tid = threadIdx.x, w = tid >> 6, lane = tid & 63;
  const int wr = w >> 1, wc = w & 1, lrow = lane & 15, lk = (lane >> 4) * 8;
  f32x4 acc[4][4];
#pragma unroll
  for (int i = 0; i < 4; ++i)
#pragma unroll
    for (int j = 0; j < 4; ++j) acc[i][j] = (f32x4)(0.f);
  for (int k0 = 0; k0 < II; k0 += 32) {
#pragma unroll
    for (int l = 0; l < 2; ++l) {
      const int idx = tid + l * 256, row = idx >> 2, kq8 = idx & 3;
      *(uint4*)&As[row][kq8 * 8] = *(const uint4*)(hid + (size_t)(t0 + row) * II + k0 + kq8 * 8);
    }
#pragma unroll
    for (int l = 0; l < 2; ++l) {
      const int idx = tid + l * 256, col = idx & 127, kq8 = idx >> 7;
      union { unsigned short u[8]; uint4 v; } pk;
#pragma unroll
      for (int kk = 0; kk < 8; ++kk) pk.u[kk] = f2bf(Wd[(size_t)(k0 + kq8 * 8 + kk) * HH + h0 + col]);
      *(uint4*)&Bs[col][kq8 * 8] = pk.v;
    }
    __syncthreads();
    bf16x8 af[4], bfr[4];
#pragma unroll
    for (int mi = 0; mi < 4; ++mi) af[mi] = *(const bf16x8*)&As[wr * 64 + mi * 16 + lrow][lk];
#pragma unroll
    for (int nj = 0; nj < 4; ++nj) bfr[nj] = *(const bf16x8*)&Bs[wc * 64 + nj * 16 + lrow][lk];
#pragma unroll
    for (int mi = 0; mi < 4; ++mi)
#pragma unroll
      for (int nj = 0; nj < 4; ++nj)
        acc[mi][nj] = __builtin_amdgcn_mfma_f32_16x16x32_bf16(af[mi], bfr[nj], acc[mi][nj], 0, 0, 0);
    __syncthreads();
  }
  const float4* ha4 = (const float4*)ha;
  const float4* B4 = (const float4*)Bdn;
#pragma unroll
  for (int nj = 0; nj < 4; ++nj) {
    const int coln = h0 + wc * 64 + nj * 16 + lrow;
    const float4 b0 = B4[coln * 2], b1 = B4[coln * 2 + 1];
#pragma unroll
    for (int mi = 0; mi < 4; ++mi) {
      const int tb = t0 + wr * 64 + mi * 16 + (lane >> 4) * 4;
#pragma unroll
      for (int j = 0; j < 4; ++j) {
        const int t = tb + j;
        const float4 hr0 = ha4[t * 2], hr1 = ha4[t * 2 + 1];
        out[(size_t)t * HH + coln] = acc[mi][nj][j] + SCAL * (dot4(hr0, b0) + dot4(hr1, b1));
      }
    }
  }
}

extern "C" void kernel_launch(void* const* d_in, const int* in_sizes, int n_in,
                              void* d_out, int out_size, void* d_ws, size_t ws_size,
                              hipStream_t stream) {
  const float* x   = (const float*)d_in[0];
  const float* Wgu = (const float*)d_in[1];
  const float* Wdn = (const float*)d_in[2];
  const float* Agu = (const float*)d_in[3];
  const float* Bgu = (const float*)d_in[4];
  const float* Adn = (const float*)d_in[5];
  const float* Bdn = (const float*)d_in[6];
  float* out = (float*)d_out;

  char* ws = (char*)d_ws;
  unsigned short* hidden = (unsigned short*)ws;                      //  32 MB
  const size_t OFF_XB  = (size_t)NROW * II * 2;                      //  32 MB
  const size_t OFF_WGU = OFF_XB + (size_t)NROW * HH * 2;             //  48 MB
  const size_t OFF_WDN = OFF_WGU + (size_t)NE * FF2 * HH * 2;        // 112 MB
  const size_t OFF_XA  = OFF_WDN + (size_t)NE * HH * II * 2;         // 144 MB
  const size_t OFF_HA  = OFF_XA + (size_t)NROW * RR * 4;
  const size_t NEED    = OFF_HA + (size_t)NROW * RR * 4;

  if (ws_size >= NEED) {
    unsigned short* xb   = (unsigned short*)(ws + OFF_XB);
    unsigned short* WguT = (unsigned short*)(ws + OFF_WGU);
    unsigned short* WdnT = (unsigned short*)(ws + OFF_WDN);
    float* xa = (float*)(ws + OFF_XA);
    float* ha = (float*)(ws + OFF_HA);

    convx_kernel<<<(NROW * HH) / (256 * 8), 256, 0, stream>>>(x, xb);
    transconv_gu_kernel<<<NE * 16 * 64, 256, 0, stream>>>(Wgu, WguT);
    transconv_dn_kernel<<<NE * 32 * 16, 256, 0, stream>>>(Wdn, WdnT);
    rowdot_kernel<HH><<<NROW / 4, 256, 0, stream>>>(x, Agu, xa);
    gemm1_bt_kernel<<<NE * 8 * 32, 256, 0, stream>>>(xb, WguT, xa, Bgu, hidden);
    rowdot_bf16_kernel<<<NROW / 4, 256, 0, stream>>>(hidden, Adn, ha);
    gemm2_bt_kernel<<<NE * 8 * 8, 256, 0, stream>>>(hidden, WdnT, ha, Bdn, out);
  } else {
    float* xa = (float*)(ws + OFF_XB);
    float* ha = xa + (size_t)NROW * RR;
    rowdot_kernel<HH><<<NROW / 4, 256, 0, stream>>>(x, Agu, xa);
    gemm1_conv_kernel<<<NE * 8 * 32, 256, 0, stream>>>(x, Wgu, xa, Bgu, hidden);
    rowdot_bf16_kernel<<<NROW / 4, 256, 0, stream>>>(hidden, Adn, ha);
    gemm2_conv_kernel<<<NE * 8 * 8, 256, 0, stream>>>(hidden, Wdn, ha, Bdn, out);
  }
}